// Round 1
// 2495.991 us; speedup vs baseline: 1.1627x; 1.1627x over previous
//
#include <hip/hip_runtime.h>

typedef unsigned short u16;
typedef float f32x4 __attribute__((ext_vector_type(4)));
typedef short bf16x8 __attribute__((ext_vector_type(8)));

constexpr int Tc = 8192;   // tokens per batch

#define DEVINL __device__ __forceinline__

DEVINL float b2f(u16 u) { union { unsigned i; float f; } v; v.i = ((unsigned)u) << 16; return v.f; }
DEVINL u16 f2b(float f) {
    union { float f; unsigned i; } v; v.f = f;
    unsigned r = v.i + 0x7fffu + ((v.i >> 16) & 1u);
    return (u16)(r >> 16);
}
DEVINL float silu_f(float x) { return x / (1.f + __expf(-x)); }

#define GLDS(gp, lp) __builtin_amdgcn_global_load_lds((const __attribute__((address_space(1))) void*)(gp), (__attribute__((address_space(3))) void*)(lp), 16, 0, 0)

// ---------------- weight convert + transpose: out[n][k] = bf16(in[k][n]), in is RxC ----------------
__global__ void wtrans(const float* __restrict__ in, u16* __restrict__ out, int R, int C)
{
    __shared__ float tile[32][33];
    const int bx = blockIdx.x * 32, by = blockIdx.y * 32;
    const int tx = threadIdx.x, ty = threadIdx.y;
#pragma unroll
    for (int j = 0; j < 32; j += 8)
        tile[ty + j][tx] = in[(size_t)(by + ty + j) * C + bx + tx];
    __syncthreads();
#pragma unroll
    for (int j = 0; j < 32; j += 8)
        out[(size_t)(bx + ty + j) * R + by + tx] = f2b(tile[tx][ty + j]);
}

// ---------------- rmsnorm (row of 1024) -> bf16 ----------------
__global__ __launch_bounds__(256)
void rmsnorm_bf16(const float* __restrict__ x, const float* __restrict__ w, u16* __restrict__ out)
{
    __shared__ float red[256];
    const int tid = threadIdx.x;
    const size_t row = blockIdx.x;
    const float4 xv = ((const float4*)(x + row * 1024))[tid];
    float s = xv.x * xv.x + xv.y * xv.y + xv.z * xv.z + xv.w * xv.w;
    red[tid] = s;
    __syncthreads();
#pragma unroll
    for (int o = 128; o > 0; o >>= 1) {
        if (tid < o) red[tid] += red[tid + o];
        __syncthreads();
    }
    const float rinv = rsqrtf(red[0] * (1.f / 1024.f) + 1e-6f);
    const float4 wv = ((const float4*)w)[tid];
    ushort4 pk = make_ushort4(f2b(xv.x * rinv * wv.x), f2b(xv.y * rinv * wv.y),
                              f2b(xv.z * rinv * wv.z), f2b(xv.w * rinv * wv.w));
    ((ushort4*)(out + row * 1024))[tid] = pk;
}

// ---------------- bf16 GEMM: C[M,N] = A[M,K] @ Bt[N,K]^T (m97 structure) ----------------
// EPI 0: store bf16. EPI 1: store fp32 = acc + Res. EPI 2: store bf16 = silu(Other)*acc.
template <int EPI>
__global__ __launch_bounds__(256)
void gemm_bf16(const u16* __restrict__ A, const u16* __restrict__ Bt,
               void* __restrict__ Out, const float* __restrict__ Res,
               const u16* __restrict__ Other, int N, int K)
{
    __shared__ __align__(16) u16 lsA[128 * 64];
    __shared__ __align__(16) u16 lsB[128 * 64];
    const int tid = threadIdx.x;
    const int wave = tid >> 6, lane = tid & 63;
    const int quad = lane >> 4, l15 = lane & 15;
    const int mBlk = blockIdx.y * 128, nBlk = blockIdx.x * 128;
    const int wm = (wave >> 1) * 64, wn = (wave & 1) * 64;

    f32x4 acc[4][4] = {};

    const int sRow = tid >> 3;
    const int sCol = (tid & 7) * 8;
    const u16* gA = A + (size_t)(mBlk + sRow) * K + sCol;
    const u16* gB = Bt + (size_t)(nBlk + sRow) * K + sCol;
    u16* lA = lsA + wave * 512;
    u16* lB = lsB + wave * 512;

    for (int k0 = 0; k0 < K; k0 += 64) {
        __syncthreads();
#pragma unroll
        for (int i = 0; i < 4; ++i) {
            GLDS(gA + (size_t)i * 32 * K + k0, lA + i * 2048);
            GLDS(gB + (size_t)i * 32 * K + k0, lB + i * 2048);
        }
        __syncthreads();
#pragma unroll
        for (int ks = 0; ks < 2; ++ks) {
            const int ko = ks * 32 + quad * 8;
            bf16x8 af[4], bfr[4];
#pragma unroll
            for (int mt = 0; mt < 4; ++mt) af[mt] = *(const bf16x8*)&lsA[(wm + mt * 16 + l15) * 64 + ko];
#pragma unroll
            for (int nt = 0; nt < 4; ++nt) bfr[nt] = *(const bf16x8*)&lsB[(wn + nt * 16 + l15) * 64 + ko];
#pragma unroll
            for (int mt = 0; mt < 4; ++mt)
#pragma unroll
                for (int nt = 0; nt < 4; ++nt)
                    acc[mt][nt] = __builtin_amdgcn_mfma_f32_16x16x32_bf16(af[mt], bfr[nt], acc[mt][nt], 0, 0, 0);
        }
    }
#pragma unroll
    for (int mt = 0; mt < 4; ++mt)
#pragma unroll
        for (int nt = 0; nt < 4; ++nt)
#pragma unroll
            for (int r = 0; r < 4; ++r) {
                const int row = mBlk + wm + mt * 16 + quad * 4 + r;
                const int col = nBlk + wn + nt * 16 + l15;
                const size_t idx = (size_t)row * N + col;
                const float vacc = acc[mt][nt][r];
                if (EPI == 0) {
                    ((u16*)Out)[idx] = f2b(vacc);
                } else if (EPI == 1) {
                    ((float*)Out)[idx] = vacc + Res[idx];
                } else {
                    const float g = b2f(Other[idx]);
                    ((u16*)Out)[idx] = f2b(silu_f(g) * vacc);
                }
            }
}

// ---------------- retention pass A (conv+silu+rope fused): Z^T[e][d] per chunk ----------------
// qkv: Tc x 3072 pre-activations (q|k|v). Grid: 1024 blocks = h*128 + n (b handled by pointer).
// LDS time-multiplex: one 'pre' halo buffer reused for k then v phase -> 49920 B -> 3 blocks/CU.
__global__ __launch_bounds__(256)
void retA(const u16* __restrict__ qkv, const float* __restrict__ cwk,
          const float* __restrict__ cwv, u16* __restrict__ S)
{
    __shared__ __align__(16) u16 pre[67 * 128];
    __shared__ __align__(16) u16 lk[64 * 128];
    __shared__ __align__(16) u16 lv[64 * 128];
    const int blk = blockIdx.x;
    const int n = blk & 127, h = blk >> 7;
    const int tid = threadIdx.x;
    const int t0 = n * 64;
    const float lg2 = log2f(1.f - exp2f(-5.f - (float)h));

    // ---- phase K: stage halo (67 rows x 128) of k pre-activations
    for (int idx = tid; idx < 2144; idx += 256) {
        const int r = idx >> 5;
        const int c4 = (idx & 31) * 4;
        const int t = t0 - 3 + r;
        ushort4 kz = make_ushort4(0, 0, 0, 0);
        if (t >= 0) kz = *(const ushort4*)&qkv[(size_t)t * 3072 + 1024 + h * 128 + c4];
        *(ushort4*)&pre[idx * 4] = kz;
    }
    __syncthreads();
#pragma unroll
    for (int w = 0; w < 16; ++w) {
        const int item = tid + w * 256;
        const int i = item >> 6, dd = item & 63;
        float k1 = 0, k2 = 0;
#pragma unroll
        for (int j = 0; j < 4; ++j) {
            const int r = (i + j) * 128;
            k1 += b2f(pre[r + dd]) * cwk[(h * 128 + dd) * 4 + j];
            k2 += b2f(pre[r + dd + 64]) * cwk[(h * 128 + dd + 64) * 4 + j];
        }
        k1 = silu_f(k1); k2 = silu_f(k2);
        const float invf = exp2f(-(float)dd * (13.287712379549449f / 64.f));
        float sn, cs;
        sincosf((float)(t0 + i) * invf, &sn, &cs);
        lk[i * 128 + dd] = f2b(k1 * cs - k2 * sn);
        lk[i * 128 + dd + 64] = f2b(k1 * sn + k2 * cs);
    }
    __syncthreads();
    // ---- phase V: stage halo of v pre-activations into the same buffer
    for (int idx = tid; idx < 2144; idx += 256) {
        const int r = idx >> 5;
        const int c4 = (idx & 31) * 4;
        const int t = t0 - 3 + r;
        ushort4 vz = make_ushort4(0, 0, 0, 0);
        if (t >= 0) vz = *(const ushort4*)&qkv[(size_t)t * 3072 + 2048 + h * 128 + c4];
        *(ushort4*)&pre[idx * 4] = vz;
    }
    __syncthreads();
#pragma unroll
    for (int w = 0; w < 16; ++w) {
        const int item = tid + w * 256;
        const int i = item >> 6, dd = item & 63;
        float v1 = 0, v2 = 0;
#pragma unroll
        for (int j = 0; j < 4; ++j) {
            const int r = (i + j) * 128;
            v1 += b2f(pre[r + dd]) * cwv[(h * 128 + dd) * 4 + j];
            v2 += b2f(pre[r + dd + 64]) * cwv[(h * 128 + dd + 64) * 4 + j];
        }
        lv[i * 128 + dd] = f2b(silu_f(v1));
        lv[i * 128 + dd + 64] = f2b(silu_f(v2));
    }
    __syncthreads();
    // Z^T[e][d] = sum_i kdec_i * v[i][e] * k[i][d]
    const int e0 = (tid >> 3) * 4, d0 = (tid & 7) * 16;
    float acc[4][16] = {};
    for (int i = 0; i < 64; ++i) {
        const float kdec = exp2f(lg2 * (float)(63 - i));
        float kk[16];
#pragma unroll
        for (int c4 = 0; c4 < 4; ++c4) {
            const ushort4 kv = *(const ushort4*)&lk[i * 128 + d0 + c4 * 4];
            kk[c4 * 4 + 0] = b2f(kv.x); kk[c4 * 4 + 1] = b2f(kv.y);
            kk[c4 * 4 + 2] = b2f(kv.z); kk[c4 * 4 + 3] = b2f(kv.w);
        }
        const ushort4 vv4 = *(const ushort4*)&lv[i * 128 + e0];
        float vv[4] = { b2f(vv4.x) * kdec, b2f(vv4.y) * kdec, b2f(vv4.z) * kdec, b2f(vv4.w) * kdec };
#pragma unroll
        for (int j = 0; j < 4; ++j)
#pragma unroll
            for (int c = 0; c < 16; ++c) acc[j][c] += vv[j] * kk[c];
    }
    const size_t base = (size_t)blk * 16384;
#pragma unroll
    for (int j = 0; j < 4; ++j)
#pragma unroll
        for (int c = 0; c < 16; c += 4) {
            ushort4 pk = make_ushort4(f2b(acc[j][c]), f2b(acc[j][c + 1]), f2b(acc[j][c + 2]), f2b(acc[j][c + 3]));
            *(ushort4*)&S[base + (size_t)(e0 + j) * 128 + d0 + c] = pk;
        }
}

// ---------------- retention scan: in-place S_n = S_{n-1}*cdec + Z_{n-1} (8 bh-pairs) ----------------
__global__ __launch_bounds__(256)
void retScan(u16* __restrict__ S)
{
    const int g = blockIdx.x * 256 + threadIdx.x;   // 0..131071
    const int el = g & 16383;
    const int bh = g >> 14;                          // 0..7 (= h)
    const float lg2 = log2f(1.f - exp2f(-5.f - (float)bh));
    const float cdec = exp2f(lg2 * 64.f);
    float run = 0.f;
    const size_t p = (size_t)bh * (128 * 16384) + el;
    u16 nxt = S[p];
    for (int n = 0; n < 128; ++n) {
        const float z = b2f(nxt);
        if (n < 127) nxt = S[p + (size_t)(n + 1) * 16384];
        S[p + (size_t)n * 16384] = f2b(run);
        run = run * cdec + z;
    }
}

// ---------------- retention pass B (conv+silu+rope fused) + gating group-norm ----------------
// gio: in = gate pre-activation (Tc x 1024), overwritten in place with gated output.
// LDS time-multiplex: one 'pre' halo buffer reused across v, k, q phases.
// 76544 B total -> 2 blocks/CU (was 111104 -> 1 block/CU, the occupancy killer).
// sincos shared between k-rope and q-rope is cached in 32 VGPRs across the K->Q phases.
__global__ __launch_bounds__(256, 2)
void retB(const u16* __restrict__ qkv, const u16* __restrict__ S,
          const float* __restrict__ cwq, const float* __restrict__ cwk,
          const float* __restrict__ cwv, const float* __restrict__ gnw,
          u16* __restrict__ gio)
{
    __shared__ __align__(16) u16 pre[67 * 128];
    __shared__ __align__(16) u16 lq[64 * 128];
    __shared__ __align__(16) u16 lk[64 * 128];
    __shared__ __align__(16) u16 lvt[128 * 72];
    __shared__ __align__(16) u16 latt[64 * 64];
    const int blk = blockIdx.x;
    const int n = blk & 127, h = blk >> 7;
    const int tid = threadIdx.x, wave = tid >> 6, lane = tid & 63;
    const int quad = lane >> 4, l15 = lane & 15;
    const int t0 = n * 64;
    const float lg2 = log2f(1.f - exp2f(-5.f - (float)h));
    const float scale = 0.08838834764831845f;  // 128^-0.5

    // ---- phase V: stage v halo, conv+silu -> lvt (transposed)
    for (int idx = tid; idx < 2144; idx += 256) {
        const int r = idx >> 5;
        const int c4 = (idx & 31) * 4;
        const int t = t0 - 3 + r;
        ushort4 vz = make_ushort4(0, 0, 0, 0);
        if (t >= 0) vz = *(const ushort4*)&qkv[(size_t)t * 3072 + 2048 + h * 128 + c4];
        *(ushort4*)&pre[idx * 4] = vz;
    }
    __syncthreads();
#pragma unroll
    for (int w = 0; w < 16; ++w) {
        const int item = tid + w * 256;
        const int i = item >> 6, dd = item & 63;
        float v1 = 0, v2 = 0;
#pragma unroll
        for (int j = 0; j < 4; ++j) {
            const int r = (i + j) * 128;
            v1 += b2f(pre[r + dd]) * cwv[(h * 128 + dd) * 4 + j];
            v2 += b2f(pre[r + dd + 64]) * cwv[(h * 128 + dd + 64) * 4 + j];
        }
        lvt[dd * 72 + i] = f2b(silu_f(v1));
        lvt[(dd + 64) * 72 + i] = f2b(silu_f(v2));
    }
    __syncthreads();

    // ---- phase K: stage k halo, conv+silu+rope -> lk; cache sincos in regs
    for (int idx = tid; idx < 2144; idx += 256) {
        const int r = idx >> 5;
        const int c4 = (idx & 31) * 4;
        const int t = t0 - 3 + r;
        ushort4 kz = make_ushort4(0, 0, 0, 0);
        if (t >= 0) kz = *(const ushort4*)&qkv[(size_t)t * 3072 + 1024 + h * 128 + c4];
        *(ushort4*)&pre[idx * 4] = kz;
    }
    __syncthreads();
    float snr[16], csr[16];
#pragma unroll
    for (int w = 0; w < 16; ++w) {
        const int item = tid + w * 256;
        const int i = item >> 6, dd = item & 63;
        float k1 = 0, k2 = 0;
#pragma unroll
        for (int j = 0; j < 4; ++j) {
            const int r = (i + j) * 128;
            k1 += b2f(pre[r + dd]) * cwk[(h * 128 + dd) * 4 + j];
            k2 += b2f(pre[r + dd + 64]) * cwk[(h * 128 + dd + 64) * 4 + j];
        }
        k1 = silu_f(k1); k2 = silu_f(k2);
        const float invf = exp2f(-(float)dd * (13.287712379549449f / 64.f));
        sincosf((float)(t0 + i) * invf, &snr[w], &csr[w]);
        lk[i * 128 + dd] = f2b(k1 * csr[w] - k2 * snr[w]);
        lk[i * 128 + dd + 64] = f2b(k1 * snr[w] + k2 * csr[w]);
    }
    __syncthreads();

    // ---- phase Q: stage q halo, conv+silu+rope (reuse sincos) -> lq
    for (int idx = tid; idx < 2144; idx += 256) {
        const int r = idx >> 5;
        const int c4 = (idx & 31) * 4;
        const int t = t0 - 3 + r;
        ushort4 qz = make_ushort4(0, 0, 0, 0);
        if (t >= 0) qz = *(const ushort4*)&qkv[(size_t)t * 3072 + h * 128 + c4];
        *(ushort4*)&pre[idx * 4] = qz;
    }
    __syncthreads();
#pragma unroll
    for (int w = 0; w < 16; ++w) {
        const int item = tid + w * 256;
        const int i = item >> 6, dd = item & 63;
        float q1 = 0, q2 = 0;
#pragma unroll
        for (int j = 0; j < 4; ++j) {
            const int r = (i + j) * 128;
            q1 += b2f(pre[r + dd]) * cwq[(h * 128 + dd) * 4 + j];
            q2 += b2f(pre[r + dd + 64]) * cwq[(h * 128 + dd + 64) * 4 + j];
        }
        q1 = silu_f(q1); q2 = silu_f(q2);
        lq[i * 128 + dd] = f2b((q1 * csr[w] - q2 * snr[w]) * scale);
        lq[i * 128 + dd + 64] = f2b((q1 * snr[w] + q2 * csr[w]) * scale);
    }
    __syncthreads();

    const int iB = wave * 16;
    bf16x8 aq[4];
#pragma unroll
    for (int ks = 0; ks < 4; ++ks) aq[ks] = *(const bf16x8*)&lq[(iB + l15) * 128 + ks * 32 + quad * 8];
    // att = (q*scale) @ K^T, masked+decayed, into LDS (bf16)
#pragma unroll
    for (int jt = 0; jt < 4; ++jt) {
        f32x4 c = {};
#pragma unroll
        for (int ks = 0; ks < 4; ++ks) {
            const bf16x8 bk = *(const bf16x8*)&lk[(jt * 16 + l15) * 128 + ks * 32 + quad * 8];
            c = __builtin_amdgcn_mfma_f32_16x16x32_bf16(aq[ks], bk, c, 0, 0, 0);
        }
#pragma unroll
        for (int r = 0; r < 4; ++r) {
            const int i_ = iB + quad * 4 + r;
            const int j_ = jt * 16 + l15;
            const float v = (i_ >= j_) ? c[r] * exp2f(lg2 * (float)(i_ - j_)) : 0.f;
            latt[i_ * 64 + j_] = f2b(v);
        }
    }
    // cross-scaled q fragments
    bf16x8 ax[4];
    {
        const float cross = exp2f(lg2 * (float)(iB + l15 + 1));
#pragma unroll
        for (int ks = 0; ks < 4; ++ks) {
            bf16x8 o;
#pragma unroll
            for (int j = 0; j < 8; ++j) o[j] = (short)f2b(b2f((u16)aq[ks][j]) * cross);
            ax[ks] = o;
        }
    }
    bf16x8 aat[2];
#pragma unroll
    for (int k2 = 0; k2 < 2; ++k2) aat[k2] = *(const bf16x8*)&latt[(iB + l15) * 64 + k2 * 32 + quad * 8];
    const size_t Sb = (size_t)blk * 16384;
    f32x4 oc[8];
#pragma unroll
    for (int et = 0; et < 8; ++et) {
        f32x4 c = {};
#pragma unroll
        for (int k2 = 0; k2 < 2; ++k2) {
            const bf16x8 bv = *(const bf16x8*)&lvt[(et * 16 + l15) * 72 + k2 * 32 + quad * 8];
            c = __builtin_amdgcn_mfma_f32_16x16x32_bf16(aat[k2], bv, c, 0, 0, 0);
        }
#pragma unroll
        for (int ks = 0; ks < 4; ++ks) {
            const bf16x8 bs = *(const bf16x8*)&S[Sb + (size_t)(et * 16 + l15) * 128 + ks * 32 + quad * 8];
            c = __builtin_amdgcn_mfma_f32_16x16x32_bf16(ax[ks], bs, c, 0, 0, 0);
        }
        oc[et] = c;
    }
    // epilogue: per-row group rmsnorm (DV=128) * silu(g), in-place over gate buffer
#pragma unroll
    for (int r = 0; r < 4; ++r) {
        float ss = 0.f;
#pragma unroll
        for (int et = 0; et < 8; ++et) ss += oc[et][r] * oc[et][r];
        ss += __shfl_xor(ss, 1); ss += __shfl_xor(ss, 2);
        ss += __shfl_xor(ss, 4); ss += __shfl_xor(ss, 8);
        const float rinv = rsqrtf(ss * (1.f / 128.f) + 1e-5f);
        const int i_ = iB + quad * 4 + r;
        const size_t row = (size_t)(t0 + i_);
#pragma unroll
        for (int et = 0; et < 8; ++et) {
            const int e = et * 16 + l15;
            const size_t gi = row * 1024 + h * 128 + e;
            const float gv = b2f(gio[gi]);
            gio[gi] = f2b(oc[et][r] * rinv * gnw[e] * silu_f(gv));
        }
    }
}

// ---------------- launch ----------------
extern "C" void kernel_launch(void* const* d_in, const int* in_sizes, int n_in,
                              void* d_out, int out_size, void* d_ws, size_t ws_size,
                              hipStream_t stream)
{
    const float* hidden = (const float*)d_in[0];
    const float* ln1 = (const float*)d_in[1];
    const float* ln2 = (const float*)d_in[2];
    const float* wq = (const float*)d_in[3];
    const float* wk = (const float*)d_in[4];
    const float* wv = (const float*)d_in[5];
    const float* wg = (const float*)d_in[6];
    const float* wo = (const float*)d_in[7];
    const float* cq = (const float*)d_in[8];
    const float* ck = (const float*)d_in[9];
    const float* cv = (const float*)d_in[10];
    const float* gnw = (const float*)d_in[11];
    const float* wgate = (const float*)d_in[12];
    const float* wup = (const float*)d_in[13];
    const float* wdown = (const float*)d_in[14];
    float* out = (float*)d_out;

    char* ws = (char*)d_ws;
    u16* W3T = (u16*)(ws + 0);              // 3072x1024 bf16 = 6,291,456 B
    u16* WGm = (u16*)(ws + 6291456);        // 1024x1024 = 2,097,152
    u16* WOT = (u16*)(ws + 8388608);        // 2,097,152
    u16* WGT = (u16*)(ws + 10485760);       // 2816x1024 = 5,767,168
    u16* WUT = (u16*)(ws + 16252928);       // 5,767,168
    u16* WDT = (u16*)(ws + 22020096);       // 1024x2816 = 5,767,168
    u16* XNb  = (u16*)(ws + 27787264);      // 8192x1024 bf16 = 16,777,216
    u16* Gb   = (u16*)(ws + 44564480);      // 8192x1024 bf16 = 16,777,216 (gate -> gated o)
    u16* QKVb = (u16*)(ws + 61341696);      // 8192x3072 bf16 = 50,331,648
    u16* SBb  = (u16*)(ws + 111673344);     // 1024 chunks x 16384 bf16 = 33,554,432
    u16* GATEb = (u16*)(ws + 61341696);     // 8192x2816 = 46,137,344 (aliases QKVb, MLP phase)
    u16* ACTb  = (u16*)(ws + 107479040);    // 46,137,344 (aliases QKVb tail + SBb) -> ends 153,616,384

    dim3 tb(32, 8);
    wtrans<<<dim3(32, 32), tb, 0, stream>>>(wq, W3T, 1024, 1024);
    wtrans<<<dim3(32, 32), tb, 0, stream>>>(wk, W3T + 1048576, 1024, 1024);
    wtrans<<<dim3(32, 32), tb, 0, stream>>>(wv, W3T + 2097152, 1024, 1024);
    wtrans<<<dim3(32, 32), tb, 0, stream>>>(wg, WGm, 1024, 1024);
    wtrans<<<dim3(32, 32), tb, 0, stream>>>(wo, WOT, 1024, 1024);
    wtrans<<<dim3(88, 32), tb, 0, stream>>>(wgate, WGT, 1024, 2816);
    wtrans<<<dim3(88, 32), tb, 0, stream>>>(wup, WUT, 1024, 2816);
    wtrans<<<dim3(32, 88), tb, 0, stream>>>(wdown, WDT, 2816, 1024);

    for (int b = 0; b < 4; ++b) {
        const float* hb = hidden + (size_t)b * 8192 * 1024;
        float* ob = out + (size_t)b * 8192 * 1024;
        rmsnorm_bf16<<<8192, 256, 0, stream>>>(hb, ln1, XNb);
        gemm_bf16<0><<<dim3(24, 64), 256, 0, stream>>>(XNb, W3T, QKVb, nullptr, nullptr, 3072, 1024);
        gemm_bf16<0><<<dim3(8, 64), 256, 0, stream>>>(XNb, WGm, Gb, nullptr, nullptr, 1024, 1024);
        retA<<<1024, 256, 0, stream>>>(QKVb, ck, cv, SBb);
        retScan<<<512, 256, 0, stream>>>(SBb);
        retB<<<1024, 256, 0, stream>>>(QKVb, SBb, cq, ck, cv, gnw, Gb);
        gemm_bf16<1><<<dim3(8, 64), 256, 0, stream>>>(Gb, WOT, ob, hb, nullptr, 1024, 1024);
        rmsnorm_bf16<<<8192, 256, 0, stream>>>(ob, ln2, XNb);
        gemm_bf16<0><<<dim3(22, 64), 256, 0, stream>>>(XNb, WGT, GATEb, nullptr, nullptr, 2816, 1024);
        gemm_bf16<2><<<dim3(22, 64), 256, 0, stream>>>(XNb, WUT, ACTb, nullptr, GATEb, 2816, 1024);
        gemm_bf16<1><<<dim3(8, 64), 256, 0, stream>>>(ACTb, WDT, ob, ob, nullptr, 1024, 2816);
    }
}

// Round 2
// 2388.695 us; speedup vs baseline: 1.2149x; 1.0449x over previous
//
#include <hip/hip_runtime.h>

typedef unsigned short u16;
typedef float f32x4 __attribute__((ext_vector_type(4)));
typedef short bf16x8 __attribute__((ext_vector_type(8)));

constexpr int Tc = 8192;   // tokens per batch

#define DEVINL __device__ __forceinline__

DEVINL float b2f(u16 u) { union { unsigned i; float f; } v; v.i = ((unsigned)u) << 16; return v.f; }
DEVINL u16 f2b(float f) {
    union { float f; unsigned i; } v; v.f = f;
    unsigned r = v.i + 0x7fffu + ((v.i >> 16) & 1u);
    return (u16)(r >> 16);
}
DEVINL float silu_f(float x) { return x / (1.f + __expf(-x)); }

#define GLDS(gp, lp) __builtin_amdgcn_global_load_lds((const __attribute__((address_space(1))) void*)(gp), (__attribute__((address_space(3))) void*)(lp), 16, 0, 0)

// ---------------- weight convert + transpose: out[n][k] = bf16(in[k][n]), in is RxC ----------------
__global__ void wtrans(const float* __restrict__ in, u16* __restrict__ out, int R, int C)
{
    __shared__ float tile[32][33];
    const int bx = blockIdx.x * 32, by = blockIdx.y * 32;
    const int tx = threadIdx.x, ty = threadIdx.y;
#pragma unroll
    for (int j = 0; j < 32; j += 8)
        tile[ty + j][tx] = in[(size_t)(by + ty + j) * C + bx + tx];
    __syncthreads();
#pragma unroll
    for (int j = 0; j < 32; j += 8)
        out[(size_t)(bx + ty + j) * R + by + tx] = f2b(tile[tx][ty + j]);
}

// ---------------- rmsnorm (row of 1024) -> bf16 ----------------
__global__ __launch_bounds__(256)
void rmsnorm_bf16(const float* __restrict__ x, const float* __restrict__ w, u16* __restrict__ out)
{
    __shared__ float red[256];
    const int tid = threadIdx.x;
    const size_t row = blockIdx.x;
    const float4 xv = ((const float4*)(x + row * 1024))[tid];
    float s = xv.x * xv.x + xv.y * xv.y + xv.z * xv.z + xv.w * xv.w;
    red[tid] = s;
    __syncthreads();
#pragma unroll
    for (int o = 128; o > 0; o >>= 1) {
        if (tid < o) red[tid] += red[tid + o];
        __syncthreads();
    }
    const float rinv = rsqrtf(red[0] * (1.f / 1024.f) + 1e-6f);
    const float4 wv = ((const float4*)w)[tid];
    ushort4 pk = make_ushort4(f2b(xv.x * rinv * wv.x), f2b(xv.y * rinv * wv.y),
                              f2b(xv.z * rinv * wv.z), f2b(xv.w * rinv * wv.w));
    ((ushort4*)(out + row * 1024))[tid] = pk;
}

// ---------------- 256x256 bf16 GEMM, 4-slot ring pipeline, counted vmcnt ----------------
// C[M,N] = A[M,K] @ Bt[N,K]^T.  8 waves (512 thr), wave = 2M x 4N, per-wave 128x64 out.
// LDS: 4 ring slots x (A 16KB + B 16KB) = 128KB. BK=32 per slot.
// LDS line layout: line lrow (0..127) holds rows lrow and lrow+128, 64B each;
// reads XOR-swizzled byte ^= (lrow&7)<<4 (T2); gload_lds dest linear, source pre-swizzled.
// Stage(t+2) issued at iter t; slot (t+2)&3 == (t-2)&3, last read before barrier(t-1) -> safe.
// Steady-state wait: vmcnt(8) (= stages t+1,t+2 in flight). Never drains to 0 mid-loop (T4).
// EPI 0: store bf16. EPI 1: store fp32 = acc + Res. EPI 2: store bf16 = silu(Other)*acc.
template <int EPI, int K>
__global__ __launch_bounds__(512, 2)
void gemm256(const u16* __restrict__ A, const u16* __restrict__ Bt,
             void* __restrict__ Out, const float* __restrict__ Res,
             const u16* __restrict__ Other, int N)
{
    constexpr int NT = K / 32;
    __shared__ __align__(16) u16 lds[65536];   // 4 slots x 16384 u16 (A:[0,8192) B:[8192,16384))
    const int tid = threadIdx.x;
    const int wave = tid >> 6, lane = tid & 63;
    const int quad = lane >> 4, l15 = lane & 15;
    const int mBlk = blockIdx.y * 256, nBlk = blockIdx.x * 256;
    const int wm = (wave >> 2) * 128;          // 0 or 128
    const int wn = (wave & 3) * 64;            // 0,64,128,192

    f32x4 acc[8][4] = {};

    // staging: per thread 2 chunks of 16B per operand per tile; source pre-swizzled
    const u16* srcA[2]; const u16* srcB[2];
    int dstOff[2];
#pragma unroll
    for (int c = 0; c < 2; ++c) {
        const int s = wave * 1024 + c * 8192 + lane * 16;   // linear byte in 16KB tile
        const int p = s ^ (((s >> 7) & 7) << 4);            // logical byte (involution)
        const int m = ((p >> 6) & 1) * 128 + (p >> 7);      // row
        const int kb = p & 63;                              // byte within 32-bf16 K-seg
        srcA[c] = A + (size_t)(mBlk + m) * K + (kb >> 1);
        srcB[c] = Bt + (size_t)(nBlk + m) * K + (kb >> 1);
        dstOff[c] = wave * 512 + c * 4096;                  // u16 units (wave-uniform)
    }

    // swizzled read offsets (u16 units within slot)
    int offA[8], offB[4];
#pragma unroll
    for (int mt = 0; mt < 8; ++mt) {
        const int lrow = mt * 16 + l15;
        int byte = lrow * 128 + (wm >> 7) * 64 + quad * 16;
        byte ^= (l15 & 7) << 4;
        offA[mt] = byte >> 1;
    }
#pragma unroll
    for (int nt = 0; nt < 4; ++nt) {
        const int lrow = (wn & 64) + nt * 16 + l15;
        int byte = lrow * 128 + (wn >> 7) * 64 + quad * 16;
        byte ^= (l15 & 7) << 4;
        offB[nt] = byte >> 1;
    }

#define STAGE(u)                                                            \
    {                                                                       \
        const int slot_ = ((u) & 3) * 16384;                                \
        GLDS(srcA[0] + (u) * 32, &lds[slot_ + dstOff[0]]);                  \
        GLDS(srcB[0] + (u) * 32, &lds[slot_ + 8192 + dstOff[0]]);           \
        GLDS(srcA[1] + (u) * 32, &lds[slot_ + dstOff[1]]);                  \
        GLDS(srcB[1] + (u) * 32, &lds[slot_ + 8192 + dstOff[1]]);           \
    }

    STAGE(0);
    STAGE(1);
    for (int t = 0; t < NT; ++t) {
        if (t + 2 < NT) STAGE(t + 2);
        if (t < NT - 2) {
            asm volatile("s_waitcnt vmcnt(8)" ::: "memory");
        } else if (t == NT - 2) {
            asm volatile("s_waitcnt vmcnt(4)" ::: "memory");
        } else {
            asm volatile("s_waitcnt vmcnt(0)" ::: "memory");
        }
        __builtin_amdgcn_s_barrier();
        __builtin_amdgcn_sched_barrier(0);   // no LDS reads above the barrier
        const int slot = (t & 3) * 16384;
        bf16x8 bw[4], aw[8];
#pragma unroll
        for (int nt = 0; nt < 4; ++nt) bw[nt] = *(const bf16x8*)&lds[slot + 8192 + offB[nt]];
#pragma unroll
        for (int mt = 0; mt < 8; ++mt) aw[mt] = *(const bf16x8*)&lds[slot + offA[mt]];
        __builtin_amdgcn_s_setprio(1);
#pragma unroll
        for (int mt = 0; mt < 8; ++mt)
#pragma unroll
            for (int nt = 0; nt < 4; ++nt)
                acc[mt][nt] = __builtin_amdgcn_mfma_f32_16x16x32_bf16(aw[mt], bw[nt], acc[mt][nt], 0, 0, 0);
        __builtin_amdgcn_s_setprio(0);
    }
#undef STAGE

#pragma unroll
    for (int mt = 0; mt < 8; ++mt)
#pragma unroll
        for (int nt = 0; nt < 4; ++nt)
#pragma unroll
            for (int r = 0; r < 4; ++r) {
                const int row = mBlk + wm + mt * 16 + quad * 4 + r;
                const int col = nBlk + wn + nt * 16 + l15;
                const size_t idx = (size_t)row * N + col;
                const float vacc = acc[mt][nt][r];
                if (EPI == 0) {
                    ((u16*)Out)[idx] = f2b(vacc);
                } else if (EPI == 1) {
                    ((float*)Out)[idx] = vacc + Res[idx];
                } else {
                    const float g = b2f(Other[idx]);
                    ((u16*)Out)[idx] = f2b(silu_f(g) * vacc);
                }
            }
}

// ---------------- retention pass A (conv+silu+rope fused): Z^T[e][d] per chunk ----------------
__global__ __launch_bounds__(256)
void retA(const u16* __restrict__ qkv, const float* __restrict__ cwk,
          const float* __restrict__ cwv, u16* __restrict__ S)
{
    __shared__ __align__(16) u16 pre[67 * 128];
    __shared__ __align__(16) u16 lk[64 * 128];
    __shared__ __align__(16) u16 lv[64 * 128];
    const int blk = blockIdx.x;
    const int n = blk & 127, h = blk >> 7;
    const int tid = threadIdx.x;
    const int t0 = n * 64;
    const float lg2 = log2f(1.f - exp2f(-5.f - (float)h));

    // ---- phase K: stage halo (67 rows x 128) of k pre-activations
    for (int idx = tid; idx < 2144; idx += 256) {
        const int r = idx >> 5;
        const int c4 = (idx & 31) * 4;
        const int t = t0 - 3 + r;
        ushort4 kz = make_ushort4(0, 0, 0, 0);
        if (t >= 0) kz = *(const ushort4*)&qkv[(size_t)t * 3072 + 1024 + h * 128 + c4];
        *(ushort4*)&pre[idx * 4] = kz;
    }
    __syncthreads();
#pragma unroll
    for (int w = 0; w < 16; ++w) {
        const int item = tid + w * 256;
        const int i = item >> 6, dd = item & 63;
        float k1 = 0, k2 = 0;
#pragma unroll
        for (int j = 0; j < 4; ++j) {
            const int r = (i + j) * 128;
            k1 += b2f(pre[r + dd]) * cwk[(h * 128 + dd) * 4 + j];
            k2 += b2f(pre[r + dd + 64]) * cwk[(h * 128 + dd + 64) * 4 + j];
        }
        k1 = silu_f(k1); k2 = silu_f(k2);
        const float invf = exp2f(-(float)dd * (13.287712379549449f / 64.f));
        float sn, cs;
        sincosf((float)(t0 + i) * invf, &sn, &cs);
        lk[i * 128 + dd] = f2b(k1 * cs - k2 * sn);
        lk[i * 128 + dd + 64] = f2b(k1 * sn + k2 * cs);
    }
    __syncthreads();
    // ---- phase V: stage halo of v pre-activations into the same buffer
    for (int idx = tid; idx < 2144; idx += 256) {
        const int r = idx >> 5;
        const int c4 = (idx & 31) * 4;
        const int t = t0 - 3 + r;
        ushort4 vz = make_ushort4(0, 0, 0, 0);
        if (t >= 0) vz = *(const ushort4*)&qkv[(size_t)t * 3072 + 2048 + h * 128 + c4];
        *(ushort4*)&pre[idx * 4] = vz;
    }
    __syncthreads();
#pragma unroll
    for (int w = 0; w < 16; ++w) {
        const int item = tid + w * 256;
        const int i = item >> 6, dd = item & 63;
        float v1 = 0, v2 = 0;
#pragma unroll
        for (int j = 0; j < 4; ++j) {
            const int r = (i + j) * 128;
            v1 += b2f(pre[r + dd]) * cwv[(h * 128 + dd) * 4 + j];
            v2 += b2f(pre[r + dd + 64]) * cwv[(h * 128 + dd + 64) * 4 + j];
        }
        lv[i * 128 + dd] = f2b(silu_f(v1));
        lv[i * 128 + dd + 64] = f2b(silu_f(v2));
    }
    __syncthreads();
    // Z^T[e][d] = sum_i kdec_i * v[i][e] * k[i][d]
    const int e0 = (tid >> 3) * 4, d0 = (tid & 7) * 16;
    float acc[4][16] = {};
    for (int i = 0; i < 64; ++i) {
        const float kdec = exp2f(lg2 * (float)(63 - i));
        float kk[16];
#pragma unroll
        for (int c4 = 0; c4 < 4; ++c4) {
            const ushort4 kv = *(const ushort4*)&lk[i * 128 + d0 + c4 * 4];
            kk[c4 * 4 + 0] = b2f(kv.x); kk[c4 * 4 + 1] = b2f(kv.y);
            kk[c4 * 4 + 2] = b2f(kv.z); kk[c4 * 4 + 3] = b2f(kv.w);
        }
        const ushort4 vv4 = *(const ushort4*)&lv[i * 128 + e0];
        float vv[4] = { b2f(vv4.x) * kdec, b2f(vv4.y) * kdec, b2f(vv4.z) * kdec, b2f(vv4.w) * kdec };
#pragma unroll
        for (int j = 0; j < 4; ++j)
#pragma unroll
            for (int c = 0; c < 16; ++c) acc[j][c] += vv[j] * kk[c];
    }
    const size_t base = (size_t)blk * 16384;
#pragma unroll
    for (int j = 0; j < 4; ++j)
#pragma unroll
        for (int c = 0; c < 16; c += 4) {
            ushort4 pk = make_ushort4(f2b(acc[j][c]), f2b(acc[j][c + 1]), f2b(acc[j][c + 2]), f2b(acc[j][c + 3]));
            *(ushort4*)&S[base + (size_t)(e0 + j) * 128 + d0 + c] = pk;
        }
}

// ---------------- retention scan: in-place S_n = S_{n-1}*cdec + Z_{n-1} (8 bh-pairs) ----------------
__global__ __launch_bounds__(256)
void retScan(u16* __restrict__ S)
{
    const int g = blockIdx.x * 256 + threadIdx.x;   // 0..131071
    const int el = g & 16383;
    const int bh = g >> 14;                          // 0..7 (= h)
    const float lg2 = log2f(1.f - exp2f(-5.f - (float)bh));
    const float cdec = exp2f(lg2 * 64.f);
    float run = 0.f;
    const size_t p = (size_t)bh * (128 * 16384) + el;
    u16 nxt = S[p];
    for (int n = 0; n < 128; ++n) {
        const float z = b2f(nxt);
        if (n < 127) nxt = S[p + (size_t)(n + 1) * 16384];
        S[p + (size_t)n * 16384] = f2b(run);
        run = run * cdec + z;
    }
}

// ---------------- retention pass B (conv+silu+rope fused) + gating group-norm ----------------
__global__ __launch_bounds__(256, 2)
void retB(const u16* __restrict__ qkv, const u16* __restrict__ S,
          const float* __restrict__ cwq, const float* __restrict__ cwk,
          const float* __restrict__ cwv, const float* __restrict__ gnw,
          u16* __restrict__ gio)
{
    __shared__ __align__(16) u16 pre[67 * 128];
    __shared__ __align__(16) u16 lq[64 * 128];
    __shared__ __align__(16) u16 lk[64 * 128];
    __shared__ __align__(16) u16 lvt[128 * 72];
    __shared__ __align__(16) u16 latt[64 * 64];
    const int blk = blockIdx.x;
    const int n = blk & 127, h = blk >> 7;
    const int tid = threadIdx.x, wave = tid >> 6, lane = tid & 63;
    const int quad = lane >> 4, l15 = lane & 15;
    const int t0 = n * 64;
    const float lg2 = log2f(1.f - exp2f(-5.f - (float)h));
    const float scale = 0.08838834764831845f;  // 128^-0.5

    // ---- phase V: stage v halo, conv+silu -> lvt (transposed)
    for (int idx = tid; idx < 2144; idx += 256) {
        const int r = idx >> 5;
        const int c4 = (idx & 31) * 4;
        const int t = t0 - 3 + r;
        ushort4 vz = make_ushort4(0, 0, 0, 0);
        if (t >= 0) vz = *(const ushort4*)&qkv[(size_t)t * 3072 + 2048 + h * 128 + c4];
        *(ushort4*)&pre[idx * 4] = vz;
    }
    __syncthreads();
#pragma unroll
    for (int w = 0; w < 16; ++w) {
        const int item = tid + w * 256;
        const int i = item >> 6, dd = item & 63;
        float v1 = 0, v2 = 0;
#pragma unroll
        for (int j = 0; j < 4; ++j) {
            const int r = (i + j) * 128;
            v1 += b2f(pre[r + dd]) * cwv[(h * 128 + dd) * 4 + j];
            v2 += b2f(pre[r + dd + 64]) * cwv[(h * 128 + dd + 64) * 4 + j];
        }
        lvt[dd * 72 + i] = f2b(silu_f(v1));
        lvt[(dd + 64) * 72 + i] = f2b(silu_f(v2));
    }
    __syncthreads();

    // ---- phase K: stage k halo, conv+silu+rope -> lk; cache sincos in regs
    for (int idx = tid; idx < 2144; idx += 256) {
        const int r = idx >> 5;
        const int c4 = (idx & 31) * 4;
        const int t = t0 - 3 + r;
        ushort4 kz = make_ushort4(0, 0, 0, 0);
        if (t >= 0) kz = *(const ushort4*)&qkv[(size_t)t * 3072 + 1024 + h * 128 + c4];
        *(ushort4*)&pre[idx * 4] = kz;
    }
    __syncthreads();
    float snr[16], csr[16];
#pragma unroll
    for (int w = 0; w < 16; ++w) {
        const int item = tid + w * 256;
        const int i = item >> 6, dd = item & 63;
        float k1 = 0, k2 = 0;
#pragma unroll
        for (int j = 0; j < 4; ++j) {
            const int r = (i + j) * 128;
            k1 += b2f(pre[r + dd]) * cwk[(h * 128 + dd) * 4 + j];
            k2 += b2f(pre[r + dd + 64]) * cwk[(h * 128 + dd + 64) * 4 + j];
        }
        k1 = silu_f(k1); k2 = silu_f(k2);
        const float invf = exp2f(-(float)dd * (13.287712379549449f / 64.f));
        sincosf((float)(t0 + i) * invf, &snr[w], &csr[w]);
        lk[i * 128 + dd] = f2b(k1 * csr[w] - k2 * snr[w]);
        lk[i * 128 + dd + 64] = f2b(k1 * snr[w] + k2 * csr[w]);
    }
    __syncthreads();

    // ---- phase Q: stage q halo, conv+silu+rope (reuse sincos) -> lq
    for (int idx = tid; idx < 2144; idx += 256) {
        const int r = idx >> 5;
        const int c4 = (idx & 31) * 4;
        const int t = t0 - 3 + r;
        ushort4 qz = make_ushort4(0, 0, 0, 0);
        if (t >= 0) qz = *(const ushort4*)&qkv[(size_t)t * 3072 + h * 128 + c4];
        *(ushort4*)&pre[idx * 4] = qz;
    }
    __syncthreads();
#pragma unroll
    for (int w = 0; w < 16; ++w) {
        const int item = tid + w * 256;
        const int i = item >> 6, dd = item & 63;
        float q1 = 0, q2 = 0;
#pragma unroll
        for (int j = 0; j < 4; ++j) {
            const int r = (i + j) * 128;
            q1 += b2f(pre[r + dd]) * cwq[(h * 128 + dd) * 4 + j];
            q2 += b2f(pre[r + dd + 64]) * cwq[(h * 128 + dd + 64) * 4 + j];
        }
        q1 = silu_f(q1); q2 = silu_f(q2);
        lq[i * 128 + dd] = f2b((q1 * csr[w] - q2 * snr[w]) * scale);
        lq[i * 128 + dd + 64] = f2b((q1 * snr[w] + q2 * csr[w]) * scale);
    }
    __syncthreads();

    const int iB = wave * 16;
    bf16x8 aq[4];
#pragma unroll
    for (int ks = 0; ks < 4; ++ks) aq[ks] = *(const bf16x8*)&lq[(iB + l15) * 128 + ks * 32 + quad * 8];
    // att = (q*scale) @ K^T, masked+decayed, into LDS (bf16)
#pragma unroll
    for (int jt = 0; jt < 4; ++jt) {
        f32x4 c = {};
#pragma unroll
        for (int ks = 0; ks < 4; ++ks) {
            const bf16x8 bk = *(const bf16x8*)&lk[(jt * 16 + l15) * 128 + ks * 32 + quad * 8];
            c = __builtin_amdgcn_mfma_f32_16x16x32_bf16(aq[ks], bk, c, 0, 0, 0);
        }
#pragma unroll
        for (int r = 0; r < 4; ++r) {
            const int i_ = iB + quad * 4 + r;
            const int j_ = jt * 16 + l15;
            const float v = (i_ >= j_) ? c[r] * exp2f(lg2 * (float)(i_ - j_)) : 0.f;
            latt[i_ * 64 + j_] = f2b(v);
        }
    }
    // cross-scaled q fragments
    bf16x8 ax[4];
    {
        const float cross = exp2f(lg2 * (float)(iB + l15 + 1));
#pragma unroll
        for (int ks = 0; ks < 4; ++ks) {
            bf16x8 o;
#pragma unroll
            for (int j = 0; j < 8; ++j) o[j] = (short)f2b(b2f((u16)aq[ks][j]) * cross);
            ax[ks] = o;
        }
    }
    bf16x8 aat[2];
#pragma unroll
    for (int k2 = 0; k2 < 2; ++k2) aat[k2] = *(const bf16x8*)&latt[(iB + l15) * 64 + k2 * 32 + quad * 8];
    const size_t Sb = (size_t)blk * 16384;
    f32x4 oc[8];
#pragma unroll
    for (int et = 0; et < 8; ++et) {
        f32x4 c = {};
#pragma unroll
        for (int k2 = 0; k2 < 2; ++k2) {
            const bf16x8 bv = *(const bf16x8*)&lvt[(et * 16 + l15) * 72 + k2 * 32 + quad * 8];
            c = __builtin_amdgcn_mfma_f32_16x16x32_bf16(aat[k2], bv, c, 0, 0, 0);
        }
#pragma unroll
        for (int ks = 0; ks < 4; ++ks) {
            const bf16x8 bs = *(const bf16x8*)&S[Sb + (size_t)(et * 16 + l15) * 128 + ks * 32 + quad * 8];
            c = __builtin_amdgcn_mfma_f32_16x16x32_bf16(ax[ks], bs, c, 0, 0, 0);
        }
        oc[et] = c;
    }
    // epilogue: per-row group rmsnorm (DV=128) * silu(g), in-place over gate buffer
#pragma unroll
    for (int r = 0; r < 4; ++r) {
        float ss = 0.f;
#pragma unroll
        for (int et = 0; et < 8; ++et) ss += oc[et][r] * oc[et][r];
        ss += __shfl_xor(ss, 1); ss += __shfl_xor(ss, 2);
        ss += __shfl_xor(ss, 4); ss += __shfl_xor(ss, 8);
        const float rinv = rsqrtf(ss * (1.f / 128.f) + 1e-5f);
        const int i_ = iB + quad * 4 + r;
        const size_t row = (size_t)(t0 + i_);
#pragma unroll
        for (int et = 0; et < 8; ++et) {
            const int e = et * 16 + l15;
            const size_t gi = row * 1024 + h * 128 + e;
            const float gv = b2f(gio[gi]);
            gio[gi] = f2b(oc[et][r] * rinv * gnw[e] * silu_f(gv));
        }
    }
}

// ---------------- launch ----------------
extern "C" void kernel_launch(void* const* d_in, const int* in_sizes, int n_in,
                              void* d_out, int out_size, void* d_ws, size_t ws_size,
                              hipStream_t stream)
{
    const float* hidden = (const float*)d_in[0];
    const float* ln1 = (const float*)d_in[1];
    const float* ln2 = (const float*)d_in[2];
    const float* wq = (const float*)d_in[3];
    const float* wk = (const float*)d_in[4];
    const float* wv = (const float*)d_in[5];
    const float* wg = (const float*)d_in[6];
    const float* wo = (const float*)d_in[7];
    const float* cq = (const float*)d_in[8];
    const float* ck = (const float*)d_in[9];
    const float* cv = (const float*)d_in[10];
    const float* gnw = (const float*)d_in[11];
    const float* wgate = (const float*)d_in[12];
    const float* wup = (const float*)d_in[13];
    const float* wdown = (const float*)d_in[14];
    float* out = (float*)d_out;

    char* ws = (char*)d_ws;
    u16* W3T = (u16*)(ws + 0);              // 3072x1024 bf16 = 6,291,456 B
    u16* WGm = (u16*)(ws + 6291456);        // 1024x1024 = 2,097,152
    u16* WOT = (u16*)(ws + 8388608);        // 2,097,152
    u16* WGT = (u16*)(ws + 10485760);       // 2816x1024 = 5,767,168
    u16* WUT = (u16*)(ws + 16252928);       // 5,767,168
    u16* WDT = (u16*)(ws + 22020096);       // 1024x2816 = 5,767,168
    u16* XNb  = (u16*)(ws + 27787264);      // 8192x1024 bf16 = 16,777,216
    u16* Gb   = (u16*)(ws + 44564480);      // 8192x1024 bf16 = 16,777,216 (gate -> gated o)
    u16* QKVb = (u16*)(ws + 61341696);      // 8192x3072 bf16 = 50,331,648
    u16* SBb  = (u16*)(ws + 111673344);     // 1024 chunks x 16384 bf16 = 33,554,432
    u16* GATEb = (u16*)(ws + 61341696);     // 8192x2816 = 46,137,344 (aliases QKVb, MLP phase)
    u16* ACTb  = (u16*)(ws + 107479040);    // 46,137,344 (aliases QKVb tail + SBb) -> ends 153,616,384

    dim3 tb(32, 8);
    wtrans<<<dim3(32, 32), tb, 0, stream>>>(wq, W3T, 1024, 1024);
    wtrans<<<dim3(32, 32), tb, 0, stream>>>(wk, W3T + 1048576, 1024, 1024);
    wtrans<<<dim3(32, 32), tb, 0, stream>>>(wv, W3T + 2097152, 1024, 1024);
    wtrans<<<dim3(32, 32), tb, 0, stream>>>(wg, WGm, 1024, 1024);
    wtrans<<<dim3(32, 32), tb, 0, stream>>>(wo, WOT, 1024, 1024);
    wtrans<<<dim3(88, 32), tb, 0, stream>>>(wgate, WGT, 1024, 2816);
    wtrans<<<dim3(88, 32), tb, 0, stream>>>(wup, WUT, 1024, 2816);
    wtrans<<<dim3(32, 88), tb, 0, stream>>>(wdown, WDT, 2816, 1024);

    for (int b = 0; b < 4; ++b) {
        const float* hb = hidden + (size_t)b * 8192 * 1024;
        float* ob = out + (size_t)b * 8192 * 1024;
        rmsnorm_bf16<<<8192, 256, 0, stream>>>(hb, ln1, XNb);
        gemm256<0, 1024><<<dim3(12, 32), 512, 0, stream>>>(XNb, W3T, QKVb, nullptr, nullptr, 3072);
        gemm256<0, 1024><<<dim3(4, 32), 512, 0, stream>>>(XNb, WGm, Gb, nullptr, nullptr, 1024);
        retA<<<1024, 256, 0, stream>>>(QKVb, ck, cv, SBb);
        retScan<<<512, 256, 0, stream>>>(SBb);
        retB<<<1024, 256, 0, stream>>>(QKVb, SBb, cq, ck, cv, gnw, Gb);
        gemm256<1, 1024><<<dim3(4, 32), 512, 0, stream>>>(Gb, WOT, ob, hb, nullptr, 1024);
        rmsnorm_bf16<<<8192, 256, 0, stream>>>(ob, ln2, XNb);
        gemm256<0, 1024><<<dim3(11, 32), 512, 0, stream>>>(XNb, WGT, GATEb, nullptr, nullptr, 2816);
        gemm256<2, 1024><<<dim3(11, 32), 512, 0, stream>>>(XNb, WUT, ACTb, nullptr, GATEb, 2816);
        gemm256<1, 2816><<<dim3(4, 32), 512, 0, stream>>>(ACTb, WDT, ob, ob, nullptr, 1024);
    }
}